// Round 8
// baseline (2803.827 us; speedup 1.0000x reference)
//
#include <hip/hip_runtime.h>
#include <cstdint>
#include <cstddef>

typedef __attribute__((ext_vector_type(8))) short short8;   // 8 bf16 (4 VGPRs)
typedef __attribute__((ext_vector_type(2))) float f32x2;
typedef __attribute__((ext_vector_type(4))) float f32x4;

#define HH     100
#define G4     400
#define NCOL   416          // 400 gates + 5 logits + 11 pad = 26 tiles of 16
#define NTIL   26
#define KTN    3            // 3 k-tiles of 32 -> k<96 via MFMA
#define KRES   96           // k=96..99 residual in f32
#define BTOT   8192
#define TST    512
#define ROWS   32
#define HALF   16           // rows per pipeline group
#define NBLK   256
#define BLOCK  832          // 13 waves; wave w owns column tiles 2w, 2w+1
#define ZW     420          // z row stride (words)
#define TANHC  1.5f
#define EPSF   1e-9f

__device__ unsigned short d_Bhi[NTIL*KTN*64*8];  // [W_h|W_ops|0] hi, B-frag order
__device__ unsigned short d_Blo[NTIL*KTN*64*8];  // lo residual
__device__ float d_Ep2[6*G4];                    // emb @ W_x   [e][je][g]
__device__ float d_WresG[NCOL*4];                // rows 96..99 of [W_h|W_ops|0], [n][q]
__device__ float d_Z0[(size_t)BTOT*G4];          // x0 @ W_x    [b][n]

static __device__ __forceinline__ unsigned short bf16hi(float f){
  unsigned u = __float_as_uint(f);
  return (unsigned short)((u + 0x7FFFu + ((u>>16)&1u)) >> 16);   // RNE
}
static __device__ __forceinline__ float bf16f(unsigned short s){
  return __uint_as_float(((unsigned)s)<<16);
}
static __device__ __forceinline__ float frcp(float x){ return __builtin_amdgcn_rcpf(x); }
static __device__ __forceinline__ float sigf(float x){ return frcp(1.0f + __expf(-x)); }
static __device__ __forceinline__ float tanh_f(float x){ return 1.0f - 2.0f*frcp(__expf(2.0f*x) + 1.0f); }

// ---- setup kernels (unchanged from R7) -----------------------------------

__global__ void setup_bpack(const float* __restrict__ Wh, const float* __restrict__ Wops){
  int idx = blockIdx.x*blockDim.x + threadIdx.x;     // NTIL*KTN*64 = 4992
  if (idx >= NTIL*KTN*64) return;
  int tile = idx/(KTN*64), rem = idx - tile*(KTN*64), kt = rem>>6, ln = rem&63;
  int n = tile*16 + (ln & 15);
  #pragma unroll
  for (int i = 0; i < 8; ++i){
    int k = kt*32 + (ln>>4)*8 + i;                   // k < 96 always
    float w = 0.f;
    if (n < G4)          w = Wh[k*G4 + n];
    else if (n < G4+5)   w = Wops[k*5 + (n - G4)];
    unsigned short hi = bf16hi(w);
    unsigned short lo = bf16hi(w - bf16f(hi));
    d_Bhi[idx*8+i] = hi;
    d_Blo[idx*8+i] = lo;
  }
}

__global__ void setup_misc(const float* __restrict__ emb, const float* __restrict__ Wx,
                           const float* __restrict__ Wh, const float* __restrict__ Wops){
  int idx = blockIdx.x*blockDim.x + threadIdx.x;
  if (idx < 6*G4){                                   // Ep2 [e][je][g]
    int e = idx/G4, r2 = idx - e*G4, je = r2>>2, g = r2&3;
    float s = 0.f;
    for (int k = 0; k < HH; ++k) s = fmaf(emb[e*HH+k], Wx[k*G4 + g*HH + je], s);
    d_Ep2[idx] = s;
  } else if (idx < 6*G4 + NCOL*4){                   // residual rows 96..99
    int i = idx - 6*G4, n = i>>2, q = i&3;
    float w = 0.f;
    if (n < G4)        w = Wh[(KRES+q)*G4 + n];
    else if (n < G4+5) w = Wops[(KRES+q)*5 + (n - G4)];
    d_WresG[i] = w;
  }
}

__global__ __launch_bounds__(256) void setup_z0(const float* __restrict__ x0,
                                                const float* __restrict__ Wx){
  __shared__ float xs[64*101];
  const int bb = blockIdx.x * 64;                    // 128 blocks
  for (int i = threadIdx.x; i < 64*HH; i += 256){
    int r = i/HH, k = i - r*HH;
    xs[r*101 + k] = x0[(size_t)(bb + r)*HH + k];
  }
  __syncthreads();
  const int bl = threadIdx.x & 63;
  for (int ng = threadIdx.x >> 6; ng < HH; ng += 4){
    f32x4 a = {0.f,0.f,0.f,0.f};
    for (int k = 0; k < HH; ++k){
      f32x4 w = *(const f32x4*)&Wx[k*G4 + ng*4];
      a += w * xs[bl*101 + k];
    }
    *(f32x4*)&d_Z0[(size_t)(bb + bl)*G4 + ng*4] = a;
  }
}

// ---- main persistent kernel: skewed two-group pipeline -------------------
// seg alpha: G_A(t) + E_B(t-1) | barrier | seg beta: G_B(t) + E_A(t) | barrier

__global__ __launch_bounds__(BLOCK) void rnn_main(
    const float* __restrict__ u, float* __restrict__ out)
{
  __shared__ __align__(16) float z_l[2][HALF*ZW];               // 53760 B
  __shared__ __align__(16) unsigned short fhi_l[2][KTN*64*8];   //  6144 B
  __shared__ __align__(16) unsigned short flo_l[2][KTN*64*8];   //  6144 B
  __shared__ __align__(16) float hres_l[2][4*HALF];             //   512 B
  __shared__ __align__(16) float Ep2_l[6*G4];                   //  9600 B
  __shared__ __align__(16) float Wres_l[NCOL*4];                //  6656 B
  __shared__ __align__(16) float samp[5*20];                    //   400 B
  __shared__ __align__(16) float gn_l[2][HALF*5];               //   640 B
  __shared__ int op_l[2][HALF];                                 //   128 B

  const int tid  = threadIdx.x;
  const int wave = tid >> 6;
  const int lane = tid & 63;
  const int cn   = lane & 15;       // col-in-tile (B,C) / row-in-tile (A)
  const int q4   = lane >> 4;
  const int row0 = blockIdx.x * ROWS;
  const int jg2  = tid >> 4;        // E mapping: 2 cells (j0, j0+1) x 1 row
  const int rE   = tid & 15;
  const int j0   = jg2 * 2;

  for (int i = tid; i < 6*G4;   i += BLOCK) Ep2_l[i]  = d_Ep2[i];
  for (int i = tid; i < NCOL*4; i += BLOCK) Wres_l[i] = d_WresG[i];

  short8 bh[2][KTN], bl[2][KTN];
  {
    const short8* bph = (const short8*)d_Bhi;
    const short8* bpl = (const short8*)d_Blo;
    #pragma unroll
    for (int tl = 0; tl < 2; ++tl)
      #pragma unroll
      for (int kt = 0; kt < KTN; ++kt){
        int fi = ((wave*2 + tl)*KTN + kt)*64 + lane;
        bh[tl][kt] = bph[fi];
        bl[tl][kt] = bpl[fi];
      }
  }

  float c_st[2][2] = {{0.f,0.f},{0.f,0.f}};
  float lp_acc[2]  = {0.f,0.f};
  float ent_acc[2] = {0.f,0.f};

// GG: group doing GEMM at step t; EG: group doing elementwise at step tE.
// GG/EG are literal 0/1 -> all state indices constant-fold (no scratch).
#define RUN_SEGMENT(GG, EG, TE_EXPR)                                          \
  {                                                                           \
    const int tE = (TE_EXPR);                                                 \
    if (t == 0){                                                              \
      if (tid < 800){                                                         \
        _Pragma("unroll")                                                     \
        for (int ii = 0; ii < 2; ++ii){                                       \
          f32x4 v = *(const f32x4*)&d_Z0[(size_t)(row0 + GG*HALF + rE)*G4 + jg2*8 + ii*4]; \
          *(f32x4*)&z_l[GG][rE*ZW + jg2*8 + ii*4] = v;                        \
        }                                                                     \
      }                                                                       \
    } else {                                                                  \
      short8 ah[KTN], al[KTN];                                                \
      _Pragma("unroll")                                                       \
      for (int kt = 0; kt < KTN; ++kt){                                       \
        ah[kt] = *(const short8*)&fhi_l[GG][(kt*64 + lane)*8];                \
        al[kt] = *(const short8*)&flo_l[GG][(kt*64 + lane)*8];                \
      }                                                                       \
      _Pragma("unroll")                                                       \
      for (int tl = 0; tl < 2; ++tl){                                         \
        const int n = (wave*2 + tl)*16 + cn;                                  \
        f32x4 acc = {0.f,0.f,0.f,0.f};                                        \
        _Pragma("unroll")                                                     \
        for (int kt = 0; kt < KTN; ++kt){                                     \
          acc = __builtin_amdgcn_mfma_f32_16x16x32_bf16(ah[kt], bh[tl][kt], acc, 0,0,0); \
          acc = __builtin_amdgcn_mfma_f32_16x16x32_bf16(al[kt], bh[tl][kt], acc, 0,0,0); \
          acc = __builtin_amdgcn_mfma_f32_16x16x32_bf16(ah[kt], bl[tl][kt], acc, 0,0,0); \
        }                                                                     \
        f32x4 wr = *(const f32x4*)&Wres_l[n*4];                               \
        _Pragma("unroll")                                                     \
        for (int q = 0; q < 4; ++q){                                          \
          f32x4 hq = *(const f32x4*)&hres_l[GG][q*HALF + q4*4];               \
          acc += hq * wr[q];                                                  \
        }                                                                     \
        if (t < TST){                                                         \
          _Pragma("unroll")                                                   \
          for (int i = 0; i < 4; ++i)                                         \
            z_l[GG][(q4*4 + i)*ZW + n] = acc[i];                              \
        }                                                                     \
        if (wave == 12 && tl == 1 && cn < 5)                                  \
          *(f32x4*)&samp[cn*20 + q4*4] = acc;                                 \
      }                                                                       \
      if (wave == 12 && lane < HALF){                                         \
        const int r = lane;                                                   \
        float l[5];                                                           \
        _Pragma("unroll")                                                     \
        for (int o = 0; o < 5; ++o) l[o] = TANHC * tanh_f(samp[o*20 + r]);    \
        int op = 0; float best = -1e30f;                                      \
        _Pragma("unroll")                                                     \
        for (int o = 0; o < 5; ++o){                                          \
          float v = l[o] + gn_l[GG][r*5 + o];                                 \
          if (v > best){ best = v; op = o; }                                  \
        }                                                                     \
        float mx = fmaxf(fmaxf(fmaxf(l[0],l[1]), fmaxf(l[2],l[3])), l[4]);    \
        float se = 0.f;                                                       \
        _Pragma("unroll")                                                     \
        for (int o = 0; o < 5; ++o) se += __expf(l[o] - mx);                  \
        float lse = mx + __logf(se);                                          \
        float cur = lse - l[op];                                              \
        lp_acc[GG]  += cur;                                                   \
        ent_acc[GG] += cur * __expf(-cur);                                    \
        op_l[GG][r] = op;                                                     \
        out[2*BTOT + (size_t)(t-1)*BTOT + row0 + GG*HALF + r] = (float)op;    \
      }                                                                       \
    }                                                                         \
    if (tE >= 0 && tE < TST){                                                 \
      if (tid < 800){                                                         \
        f32x2 zg[4];                                                          \
        _Pragma("unroll")                                                     \
        for (int gg = 0; gg < 4; ++gg)                                        \
          zg[gg] = *(const f32x2*)&z_l[EG][rE*ZW + gg*HH + j0];               \
        if (tE > 0){                                                          \
          const int op = op_l[EG][rE];                                        \
          f32x4 e0 = *(const f32x4*)&Ep2_l[op*G4 + j0*4];                     \
          f32x4 e1 = *(const f32x4*)&Ep2_l[op*G4 + (j0+1)*4];                 \
          zg[0][0] += e0.x; zg[1][0] += e0.y; zg[2][0] += e0.z; zg[3][0] += e0.w; \
          zg[0][1] += e1.x; zg[1][1] += e1.y; zg[2][1] += e1.z; zg[3][1] += e1.w; \
        }                                                                     \
        float hv[2];                                                          \
        _Pragma("unroll")                                                     \
        for (int i = 0; i < 2; ++i){                                          \
          float cc = sigf(zg[1][i])*c_st[EG][i] + sigf(zg[0][i])*tanh_f(zg[2][i]); \
          c_st[EG][i] = cc;                                                   \
          hv[i] = sigf(zg[3][i])*tanh_f(cc);                                  \
        }                                                                     \
        if (j0 < KRES){                                                       \
          unsigned short h0 = bf16hi(hv[0]), h1 = bf16hi(hv[1]);              \
          unsigned short lo0 = bf16hi(hv[0] - bf16f(h0));                     \
          unsigned short lo1 = bf16hi(hv[1] - bf16f(h1));                     \
          const int kt = j0 >> 5;                                             \
          const int lf = rE + (((j0 >> 3) & 3) << 4);                         \
          const int hw = (kt*64 + lf)*8 + (j0 & 7);                           \
          *(unsigned*)&fhi_l[EG][hw] = (unsigned)h0  | ((unsigned)h1  << 16); \
          *(unsigned*)&flo_l[EG][hw] = (unsigned)lo0 | ((unsigned)lo1 << 16); \
        } else {                                                              \
          hres_l[EG][(j0 - KRES)*HALF + rE]     = hv[0];                      \
          hres_l[EG][(j0 - KRES + 1)*HALF + rE] = hv[1];                      \
        }                                                                     \
      } else if (tid < 816){                                                  \
        const int r = tid - 800;                                              \
        const float* up = u + ((size_t)tE*BTOT + row0 + EG*HALF + r)*5;       \
        _Pragma("unroll")                                                     \
        for (int o = 0; o < 5; ++o){                                          \
          float uu = up[o];                                                   \
          gn_l[EG][r*5 + o] = -__logf(-__logf(uu + EPSF) + EPSF);             \
        }                                                                     \
      }                                                                       \
    }                                                                         \
  }

  for (int t = 0; ; ++t){
    RUN_SEGMENT(0, 1, t-1)      // G_A(t) + E_B(t-1)
    __syncthreads();
    RUN_SEGMENT(1, 0, t)        // G_B(t) + E_A(t)
    if (t == TST) break;
    __syncthreads();
  }
#undef RUN_SEGMENT

  if (wave == 12 && lane < HALF){
    out[row0 + lane]               = lp_acc[0];
    out[row0 + HALF + lane]        = lp_acc[1];
    out[BTOT + row0 + lane]        = ent_acc[0];
    out[BTOT + row0 + HALF + lane] = ent_acc[1];
  }
}

extern "C" void kernel_launch(void* const* d_in, const int* in_sizes, int n_in,
                              void* d_out, int out_size, void* d_ws, size_t ws_size,
                              hipStream_t stream) {
  const float* x0   = (const float*)d_in[0];
  const float* Wx   = (const float*)d_in[1];
  const float* Wh   = (const float*)d_in[2];
  const float* Wops = (const float*)d_in[3];
  const float* emb  = (const float*)d_in[4];
  const float* u    = (const float*)d_in[5];
  (void)d_ws; (void)ws_size; (void)in_sizes; (void)n_in;

  setup_bpack<<<(NTIL*KTN*64 + 255)/256, 256, 0, stream>>>(Wh, Wops);
  setup_misc<<<(6*G4 + NCOL*4 + 255)/256, 256, 0, stream>>>(emb, Wx, Wh, Wops);
  setup_z0<<<BTOT/64, 256, 0, stream>>>(x0, Wx);
  rnn_main<<<NBLK, BLOCK, 0, stream>>>(u, (float*)d_out);
}